// Round 1
// 414.428 us; speedup vs baseline: 1.0278x; 1.0278x over previous
//
#include <hip/hip_runtime.h>

// Problem constants (from reference)
#define BN     16
#define NLINES 200
#define CFEAT  64
#define HIMG   256
#define WIMG   256
#define LLEN   64
#define NBINS  32

// Output element offsets (flat concat, return order)
#define O_NORM   0         // (B,N,2)      6400
#define O_CIMG   6400      // (B,N,2)      6400
#define O_CBODY  12800     // (B,N,3)      9600
#define O_PF     22400     // (B,N,64)   204800
#define O_PB     227200    // (B,N,64)   204800
#define O_VALID  432000    // (B,N)        3200
#define O_AMP    435200    // (B,N)        3200
#define O_SLOPE  438400    // (B,N)        3200
#define O_FEAT   441600    // (B,64,200,64) 13107200

#define NPTS (BN*NLINES*LLEN)   // 204800 points

struct LineGeom {
  float cix, ciy;   // centers_in_image
  float nix, niy;   // normals_in_image
  float cb0, cb1, cb2;
  bool  vdl;
};

__device__ __forceinline__ LineGeom compute_line(
    const float* __restrict__ pose, const float* __restrict__ cam,
    const float* __restrict__ tv, int b, int n)
{
  const float* P = pose + b*12;
  float R00=P[0],R01=P[1],R02=P[2];
  float R10=P[3],R11=P[4],R12=P[5];
  float R20=P[6],R21=P[7],R22=P[8];
  float t0=P[9], t1=P[10], t2=P[11];
  const float* C = cam + b*6;
  float sx=C[0], sy=C[1], fx=C[2], fy=C[3];
  float cx=C[4], cy=C[5];
  const float* T = tv + (b*NLINES + n)*8;
  float cb0=T[0], cb1=T[1], cb2=T[2];
  float nb0=T[3], nb1=T[4], nb2=T[5];
  float fg=T[6],  bg=T[7];

  float cv0 = R00*cb0 + R01*cb1 + R02*cb2 + t0;
  float cv1 = R10*cb0 + R11*cb1 + R12*cb2 + t1;
  float cv2 = R20*cb0 + R21*cb1 + R22*cb2 + t2;
  float nv0 = R00*nb0 + R01*nb1 + R02*nb2;
  float nv1 = R10*nb0 + R11*nb1 + R12*nb2;

  float z  = cv2;
  float zc = fmaxf(z, 1e-4f);
  float cix = (cv0/zc)*fx + cx;
  float ciy = (cv1/zc)*fy + cy;
  bool inb = (cix >= 0.f) && (cix <= sx - 1.f) && (ciy >= 0.f) && (ciy <= sy - 1.f);
  bool centers_valid = (z > 1e-4f) && inb;

  float nrm = fmaxf(sqrtf(nv0*nv0 + nv1*nv1), 1e-12f);
  float nix = nv0/nrm, niy = nv1/nrm;

  float contd = fminf(fg*fx/z, bg*fx/z);
  bool vdl = (contd >= 6.0f) && centers_valid;

  float px0 = cix + (-31.5f)*nix, py0 = ciy + (-31.5f)*niy;
  float px1 = cix + ( 31.5f)*nix, py1 = ciy + ( 31.5f)*niy;
  vdl = vdl && (px0 >= 0.f) && (px0 < 256.f) && (py0 >= 0.f) && (py0 < 256.f)
            && (px1 >= 0.f) && (px1 < 256.f) && (py1 >= 0.f) && (py1 < 256.f);

  LineGeom g;
  g.cix = cix; g.ciy = ciy; g.nix = nix; g.niy = niy;
  g.cb0 = cb0; g.cb1 = cb1; g.cb2 = cb2; g.vdl = vdl;
  return g;
}

__device__ __forceinline__ void point_xy(const LineGeom& g, int i, float& x, float& y)
{
  float s  = (float)i - 31.5f;
  float px = g.cix + s*g.nix;
  float py = g.ciy + s*g.niy;
  float gx = px/256.0f*2.0f - 1.0f;
  float gy = py/256.0f*2.0f - 1.0f;
  x = ((gx + 1.0f)*256.0f - 1.0f)*0.5f;
  y = ((gy + 1.0f)*256.0f - 1.0f)*0.5f;
}

// Per-point kernel: nearest-neighbor image sample -> histogram pf/pb,
// plus per-line scalar outputs. No workspace use.
__global__ __launch_bounds__(256)
void contour_points_kernel(const float* __restrict__ image,
                           const float* __restrict__ pose,
                           const float* __restrict__ cam,
                           const float* __restrict__ tv,
                           const float* __restrict__ fore,
                           const float* __restrict__ back,
                           float* __restrict__ out)
{
  int tid = blockIdx.x*256 + threadIdx.x;   // 0 .. 204799, grid exact
  int i  = tid & 63;
  int ln = tid >> 6;          // 0..3199
  int n  = ln % NLINES;
  int b  = ln / NLINES;

  LineGeom g = compute_line(pose, cam, tv, b, n);

  float x, y;
  point_xy(g, i, x, y);

  // nearest-neighbor sample of image (3 channels) -> hist -> pf/pb
  float xr = rintf(x), yr = rintf(y);       // jnp.round = half-to-even
  int xi = (int)xr, yi = (int)yr;
  bool v = (xi >= 0) && (xi < WIMG) && (yi >= 0) && (yi < HIMG);
  int xc = min(max(xi, 0), WIMG-1), yc = min(max(yi, 0), HIMG-1);
  const float* ib = image + (size_t)b*3*HIMG*WIMG + yc*WIMG + xc;
  float r0 = v ? ib[0]           : 0.f;
  float r1 = v ? ib[HIMG*WIMG]   : 0.f;
  float r2 = v ? ib[2*HIMG*WIMG] : 0.f;

  int b0 = min(max((int)(r0*32.f), 0), NBINS-1);
  int b1 = min(max((int)(r1*32.f), 0), NBINS-1);
  int b2 = min(max((int)(r2*32.f), 0), NBINS-1);
  int hidx = (b0*NBINS + b1)*NBINS + b2;

  float pf = fore[b*NBINS*NBINS*NBINS + hidx];
  float pb = back[b*NBINS*NBINS*NBINS + hidx];
  if (pf < 1e-5f && pb < 1e-5f) { pf = 1e-5f; pb = 1e-5f; }
  float ps = pf + pb;
  pf /= ps; pb /= ps;

  out[O_PF + ln*LLEN + i] = pf;
  out[O_PB + ln*LLEN + i] = pb;

  if (i == 0) {
    out[O_NORM  + ln*2 + 0] = g.nix;
    out[O_NORM  + ln*2 + 1] = g.niy;
    out[O_CIMG  + ln*2 + 0] = g.cix;
    out[O_CIMG  + ln*2 + 1] = g.ciy;
    out[O_CBODY + ln*3 + 0] = g.cb0;
    out[O_CBODY + ln*3 + 1] = g.cb1;
    out[O_CBODY + ln*3 + 2] = g.cb2;
    out[O_VALID + ln] = g.vdl ? 1.0f : 0.0f;
    out[O_AMP   + ln] = 0.43f;
    out[O_SLOPE + ln] = 0.5f;
  }
}

// Kernel G4: bilinear feature gather, 4 channels per thread, paired x-taps.
// - Geometry recomputed per thread (pose/cam/tv are wave-uniform broadcast
//   loads; ~50 VALU ops) -> no offs/wts workspace traffic at all.
// - The two x-taps of each bilinear row always lie in {xb, xb+1} where
//   xb = clamp(x0, 0, W-2), so one 8 B load per row replaces two 4 B
//   gathers (halves VMEM instructions and L1 line re-reads).
// - XCD-affine swizzle: all 50 blocks of a (b, c4) unit land on one XCD,
//   keeping its 4 feature planes (1 MB) resident in that XCD's 4 MB L2.
__global__ __launch_bounds__(256)
void contour_gather4_kernel(const float* __restrict__ feature,
                            const float* __restrict__ pose,
                            const float* __restrict__ cam,
                            const float* __restrict__ tv,
                            float* __restrict__ out)
{
  int bid = blockIdx.x;        // 0..12799
  int xcd = bid & 7;
  int q   = bid >> 3;          // 0..1599
  int j   = q % 50;            // chunk within unit
  int ug  = q / 50;            // 0..31
  int u   = ug*8 + xcd;        // 0..255  (b, c4) unit
  int b   = u >> 4;
  int c   = (u & 15) << 2;     // first of 4 channels

  int idx = j*256 + (int)threadIdx.x;  // 0..12799 within unit
  int n   = idx >> 6;
  int i   = idx & 63;

  LineGeom g = compute_line(pose, cam, tv, b, n);
  float x, y;
  point_xy(g, i, x, y);

  float x0f = floorf(x), y0f = floorf(y);
  float wx1 = x - x0f, wy1 = y - y0f;
  float wx0 = 1.0f - wx1, wy0 = 1.0f - wy1;
  int x0 = (int)x0f, y0 = (int)y0f;
  int x1 = x0 + 1,  y1 = y0 + 1;
  bool vx0 = (x0 >= 0) && (x0 < WIMG);
  bool vx1 = (x1 >= 0) && (x1 < WIMG);
  bool vy0 = (y0 >= 0) && (y0 < HIMG);
  bool vy1 = (y1 >= 0) && (y1 < HIMG);

  int xc0 = min(max(x0, 0), WIMG-1);
  int xc1 = min(max(x1, 0), WIMG-1);
  int xb  = min(max(x0, 0), WIMG-2);   // window [xb, xb+1] always covers xc0, xc1
  int yb0 = min(max(y0, 0), HIMG-1);
  int yb1 = min(max(y1, 0), HIMG-1);

  float fx0 = vx0 ? wx0 : 0.f;
  float fx1 = vx1 ? wx1 : 0.f;
  // weight on window element .x (pixel xb) and .y (pixel xb+1)
  float wa = ((xc0 == xb)   ? fx0 : 0.f) + ((xc1 == xb)   ? fx1 : 0.f);
  float wb = ((xc0 == xb+1) ? fx0 : 0.f) + ((xc1 == xb+1) ? fx1 : 0.f);
  float wyA = vy0 ? wy0 : 0.f;
  float wyB = vy1 ? wy1 : 0.f;

  const float* base = feature + ((size_t)(b*CFEAT + c) << 16);
  int o0 = yb0*WIMG + xb;
  int o1 = yb1*WIMG + xb;

  // Issue all 8 row-pair loads (4 channels x 2 rows), then combine.
  float2 r0[4], r1[4];
  #pragma unroll
  for (int k = 0; k < 4; ++k) {
    __builtin_memcpy(&r0[k], base + (size_t)k*65536 + o0, 8);
    __builtin_memcpy(&r1[k], base + (size_t)k*65536 + o1, 8);
  }

  size_t ob = (size_t)O_FEAT + (((size_t)(b*CFEAT + c))*NLINES + n)*LLEN + i;
  #pragma unroll
  for (int k = 0; k < 4; ++k) {
    float v = wyA*(wa*r0[k].x + wb*r0[k].y)
            + wyB*(wa*r1[k].x + wb*r1[k].y);
    out[ob + (size_t)k*(NLINES*LLEN)] = v;
  }
}

extern "C" void kernel_launch(void* const* d_in, const int* in_sizes, int n_in,
                              void* d_out, int out_size, void* d_ws, size_t ws_size,
                              hipStream_t stream) {
  const float* image   = (const float*)d_in[0];
  const float* feature = (const float*)d_in[1];
  const float* pose    = (const float*)d_in[2];
  const float* cam     = (const float*)d_in[3];
  const float* tv      = (const float*)d_in[4];
  const float* fore    = (const float*)d_in[5];
  const float* back    = (const float*)d_in[6];
  float* out = (float*)d_out;

  contour_points_kernel<<<NPTS/256, 256, 0, stream>>>(
      image, pose, cam, tv, fore, back, out);
  // 13107200 elems / 4 per thread / 256 = 12800 blocks
  contour_gather4_kernel<<<(BN*CFEAT*NLINES*LLEN)/(4*256), 256, 0, stream>>>(
      feature, pose, cam, tv, out);
}

// Round 2
// 405.094 us; speedup vs baseline: 1.0515x; 1.0230x over previous
//
#include <hip/hip_runtime.h>

// Problem constants (from reference)
#define BN     16
#define NLINES 200
#define CFEAT  64
#define HIMG   256
#define WIMG   256
#define LLEN   64
#define NBINS  32

// Output element offsets (flat concat, return order)
#define O_NORM   0         // (B,N,2)      6400
#define O_CIMG   6400      // (B,N,2)      6400
#define O_CBODY  12800     // (B,N,3)      9600
#define O_PF     22400     // (B,N,64)   204800
#define O_PB     227200    // (B,N,64)   204800
#define O_VALID  432000    // (B,N)        3200
#define O_AMP    435200    // (B,N)        3200
#define O_SLOPE  438400    // (B,N)        3200
#define O_FEAT   441600    // (B,64,200,64) 13107200

#define NPTS (BN*NLINES*LLEN)   // 204800 points

struct LineGeom {
  float cix, ciy;   // centers_in_image
  float nix, niy;   // normals_in_image
  float cb0, cb1, cb2;
  bool  vdl;
};

__device__ __forceinline__ LineGeom compute_line(
    const float* __restrict__ pose, const float* __restrict__ cam,
    const float* __restrict__ tv, int b, int n)
{
  const float* P = pose + b*12;
  float R00=P[0],R01=P[1],R02=P[2];
  float R10=P[3],R11=P[4],R12=P[5];
  float R20=P[6],R21=P[7],R22=P[8];
  float t0=P[9], t1=P[10], t2=P[11];
  const float* C = cam + b*6;
  float sx=C[0], sy=C[1], fx=C[2], fy=C[3];
  float cx=C[4], cy=C[5];
  const float* T = tv + (b*NLINES + n)*8;
  float cb0=T[0], cb1=T[1], cb2=T[2];
  float nb0=T[3], nb1=T[4], nb2=T[5];
  float fg=T[6],  bg=T[7];

  float cv0 = R00*cb0 + R01*cb1 + R02*cb2 + t0;
  float cv1 = R10*cb0 + R11*cb1 + R12*cb2 + t1;
  float cv2 = R20*cb0 + R21*cb1 + R22*cb2 + t2;
  float nv0 = R00*nb0 + R01*nb1 + R02*nb2;
  float nv1 = R10*nb0 + R11*nb1 + R12*nb2;

  float z  = cv2;
  float zc = fmaxf(z, 1e-4f);
  float cix = (cv0/zc)*fx + cx;
  float ciy = (cv1/zc)*fy + cy;
  bool inb = (cix >= 0.f) && (cix <= sx - 1.f) && (ciy >= 0.f) && (ciy <= sy - 1.f);
  bool centers_valid = (z > 1e-4f) && inb;

  float nrm = fmaxf(sqrtf(nv0*nv0 + nv1*nv1), 1e-12f);
  float nix = nv0/nrm, niy = nv1/nrm;

  float contd = fminf(fg*fx/z, bg*fx/z);
  bool vdl = (contd >= 6.0f) && centers_valid;

  float px0 = cix + (-31.5f)*nix, py0 = ciy + (-31.5f)*niy;
  float px1 = cix + ( 31.5f)*nix, py1 = ciy + ( 31.5f)*niy;
  vdl = vdl && (px0 >= 0.f) && (px0 < 256.f) && (py0 >= 0.f) && (py0 < 256.f)
            && (px1 >= 0.f) && (px1 < 256.f) && (py1 >= 0.f) && (py1 < 256.f);

  LineGeom g;
  g.cix = cix; g.ciy = ciy; g.nix = nix; g.niy = niy;
  g.cb0 = cb0; g.cb1 = cb1; g.cb2 = cb2; g.vdl = vdl;
  return g;
}

__device__ __forceinline__ void point_xy(const LineGeom& g, int i, float& x, float& y)
{
  float s  = (float)i - 31.5f;
  float px = g.cix + s*g.nix;
  float py = g.ciy + s*g.niy;
  float gx = px/256.0f*2.0f - 1.0f;
  float gy = py/256.0f*2.0f - 1.0f;
  x = ((gx + 1.0f)*256.0f - 1.0f)*0.5f;
  y = ((gy + 1.0f)*256.0f - 1.0f)*0.5f;
}

// Fully fused kernel: one launch for the whole op.
//
// Grid decomposition: unit u = (b, c8) of 8 feature planes; 128 units.
//   Each unit = 12,800 points = 50 blocks of 256 threads.
//   Thread = 1 point x 8 channels: 16x 8B paired-row loads (the two x-taps
//   of a bilinear row always lie in {xb, xb+1}, xb = clamp(x0,0,W-2)).
//   XCD-affine swizzle: all 50 blocks of a unit share bid%8 -> one XCD,
//   keeping its 8 planes (2 MB) resident in that XCD's 4 MB L2.
//
// Points work (NN image sample -> histogram pf/pb + per-line scalars) is
// folded into exactly one unit per b, chosen as c8 == (b&7) so the 16
// heavy units spread 2-per-XCD. Its extra gathers hide under the 16
// in-flight feature loads; no separate launch.
__global__ __launch_bounds__(256)
void contour_fused_kernel(const float* __restrict__ feature,
                          const float* __restrict__ image,
                          const float* __restrict__ pose,
                          const float* __restrict__ cam,
                          const float* __restrict__ tv,
                          const float* __restrict__ fore,
                          const float* __restrict__ back,
                          float* __restrict__ out)
{
  int bid = blockIdx.x;        // 0..6399
  int xcd = bid & 7;
  int q   = bid >> 3;          // 0..799
  int j   = q % 50;            // chunk within unit
  int ug  = q / 50;            // 0..15
  int u   = ug*8 + xcd;        // 0..127  (b, c8) unit
  int b   = u >> 3;
  int c8  = u & 7;
  int c   = c8 << 3;           // first of 8 channels

  int idx = j*256 + (int)threadIdx.x;  // 0..12799 within unit
  int n   = idx >> 6;
  int i   = idx & 63;

  LineGeom g = compute_line(pose, cam, tv, b, n);
  float x, y;
  point_xy(g, i, x, y);

  // ---- bilinear setup (paired x-taps) ----
  float x0f = floorf(x), y0f = floorf(y);
  float wx1 = x - x0f, wy1 = y - y0f;
  float wx0 = 1.0f - wx1, wy0 = 1.0f - wy1;
  int x0 = (int)x0f, y0 = (int)y0f;
  int x1 = x0 + 1,  y1 = y0 + 1;
  bool vx0 = (x0 >= 0) && (x0 < WIMG);
  bool vx1 = (x1 >= 0) && (x1 < WIMG);
  bool vy0 = (y0 >= 0) && (y0 < HIMG);
  bool vy1 = (y1 >= 0) && (y1 < HIMG);

  int xc0 = min(max(x0, 0), WIMG-1);
  int xc1 = min(max(x1, 0), WIMG-1);
  int xb  = min(max(x0, 0), WIMG-2);   // window [xb, xb+1] covers xc0, xc1
  int yb0 = min(max(y0, 0), HIMG-1);
  int yb1 = min(max(y1, 0), HIMG-1);

  float fx0 = vx0 ? wx0 : 0.f;
  float fx1 = vx1 ? wx1 : 0.f;
  float wa = ((xc0 == xb)   ? fx0 : 0.f) + ((xc1 == xb)   ? fx1 : 0.f);
  float wb = ((xc0 == xb+1) ? fx0 : 0.f) + ((xc1 == xb+1) ? fx1 : 0.f);
  float wyA = vy0 ? wy0 : 0.f;
  float wyB = vy1 ? wy1 : 0.f;
  float w00 = wyA*wa, w01 = wyA*wb;
  float w10 = wyB*wa, w11 = wyB*wb;

  const float* base = feature + ((size_t)(b*CFEAT + c) << 16);
  int o0 = yb0*WIMG + xb;
  int o1 = yb1*WIMG + xb;

  // ---- issue all 16 feature loads (8 planes x 2 rows), keep in flight ----
  float2 r0[8], r1[8];
  #pragma unroll
  for (int k = 0; k < 8; ++k) {
    __builtin_memcpy(&r0[k], base + (size_t)k*65536 + o0, 8);
    __builtin_memcpy(&r1[k], base + (size_t)k*65536 + o1, 8);
  }

  // ---- points work for exactly one unit per b (spread across XCDs) ----
  if (c8 == (b & 7)) {
    int ln = b*NLINES + n;

    float xr = rintf(x), yr = rintf(y);     // jnp.round = half-to-even
    int xi = (int)xr, yi = (int)yr;
    bool v = (xi >= 0) && (xi < WIMG) && (yi >= 0) && (yi < HIMG);
    int xc = min(max(xi, 0), WIMG-1), yc = min(max(yi, 0), HIMG-1);
    const float* ib = image + (size_t)b*3*HIMG*WIMG + yc*WIMG + xc;
    float r0i = v ? ib[0]           : 0.f;
    float r1i = v ? ib[HIMG*WIMG]   : 0.f;
    float r2i = v ? ib[2*HIMG*WIMG] : 0.f;

    int b0 = min(max((int)(r0i*32.f), 0), NBINS-1);
    int b1 = min(max((int)(r1i*32.f), 0), NBINS-1);
    int b2 = min(max((int)(r2i*32.f), 0), NBINS-1);
    int hidx = (b0*NBINS + b1)*NBINS + b2;

    float pf = fore[b*NBINS*NBINS*NBINS + hidx];
    float pb = back[b*NBINS*NBINS*NBINS + hidx];
    if (pf < 1e-5f && pb < 1e-5f) { pf = 1e-5f; pb = 1e-5f; }
    float ps = pf + pb;
    pf /= ps; pb /= ps;

    out[O_PF + ln*LLEN + i] = pf;
    out[O_PB + ln*LLEN + i] = pb;

    if (i == 0) {
      out[O_NORM  + ln*2 + 0] = g.nix;
      out[O_NORM  + ln*2 + 1] = g.niy;
      out[O_CIMG  + ln*2 + 0] = g.cix;
      out[O_CIMG  + ln*2 + 1] = g.ciy;
      out[O_CBODY + ln*3 + 0] = g.cb0;
      out[O_CBODY + ln*3 + 1] = g.cb1;
      out[O_CBODY + ln*3 + 2] = g.cb2;
      out[O_VALID + ln] = g.vdl ? 1.0f : 0.0f;
      out[O_AMP   + ln] = 0.43f;
      out[O_SLOPE + ln] = 0.5f;
    }
  }

  // ---- combine + store 8 channel outputs ----
  size_t ob = (size_t)O_FEAT + (((size_t)(b*CFEAT + c))*NLINES + n)*LLEN + i;
  #pragma unroll
  for (int k = 0; k < 8; ++k) {
    float v = fmaf(w00, r0[k].x,
              fmaf(w01, r0[k].y,
              fmaf(w10, r1[k].x,
                   w11 * r1[k].y)));
    out[ob + (size_t)k*(NLINES*LLEN)] = v;
  }
}

extern "C" void kernel_launch(void* const* d_in, const int* in_sizes, int n_in,
                              void* d_out, int out_size, void* d_ws, size_t ws_size,
                              hipStream_t stream) {
  const float* image   = (const float*)d_in[0];
  const float* feature = (const float*)d_in[1];
  const float* pose    = (const float*)d_in[2];
  const float* cam     = (const float*)d_in[3];
  const float* tv      = (const float*)d_in[4];
  const float* fore    = (const float*)d_in[5];
  const float* back    = (const float*)d_in[6];
  float* out = (float*)d_out;

  // 13107200 elems / 8 per thread / 256 = 6400 blocks, single launch
  contour_fused_kernel<<<(BN*CFEAT*NLINES*LLEN)/(8*256), 256, 0, stream>>>(
      feature, image, pose, cam, tv, fore, back, out);
}